// Round 3
// baseline (25.002 us; speedup 1.0000x reference)
//
#include <hip/hip_runtime.h>
#include <hip/hip_bf16.h>

// Nearest-neighbor sigmoid table: tab[i] = sigma(-8 + i/256), i in [0, 4352).
// Index space folded into weights: y = 256*x + 2048.5 (512*x for g-gates,
// since tanh(g) = 2*sigma(2g) - 1); trunc(y) == round-to-nearest node.
#define TABN 4352

__device__ __forceinline__ float gclamp(float y) {
    return __builtin_amdgcn_fmed3f(y, 0.0f, 4351.0f);
}

__global__ __launch_bounds__(256) void lstm_fc_nn(
    const float4* __restrict__ x4,     // [B] float4 (SEQ=4, INPUT=1)
    const float*  __restrict__ W_ih,   // [8]
    const float*  __restrict__ W_hh,   // [8,2]
    const float*  __restrict__ b_ih,   // [8]
    const float*  __restrict__ b_hh,   // [8]
    const float*  __restrict__ W_fc,   // [1,2]
    const float*  __restrict__ b_fc,   // [1]
    float* __restrict__ out,           // [B]
    int B)
{
    __shared__ float tab[TABN];
    for (int i = threadIdx.x; i < TABN; i += 256) {
        const float xv = fmaf((float)i, 0.00390625f, -8.0f);   // 1/256
        tab[i] = __fdividef(1.0f, 1.0f + __expf(-xv));
    }
    __syncthreads();

    // Gate order [i,f,g,o] x H=2: 0,1=i  2,3=f  4,5=g  6,7=o.
    float ws[8], w0[8], w1[8], bb[8];
#pragma unroll
    for (int g = 0; g < 8; ++g) {
        const float s = (g == 4 || g == 5) ? 512.0f : 256.0f;
        ws[g] = s * W_ih[g];
        w0[g] = s * W_hh[2 * g];
        w1[g] = s * W_hh[2 * g + 1];
        bb[g] = fmaf(s, b_ih[g] + b_hh[g], 2048.5f);
    }
    const float wfc0 = W_fc[0], wfc1 = W_fc[1], bfc = b_fc[0];

    const int half = B >> 1;
    const int tid = blockIdx.x * blockDim.x + threadIdx.x;
    if (tid >= half) return;

    // Two independent elements per thread for ILP on the serial chain.
    const float4 xa = x4[tid];
    const float4 xb = x4[tid + half];
    const float xs[2][4] = {{xa.x, xa.y, xa.z, xa.w}, {xb.x, xb.y, xb.z, xb.w}};

    float h0[2], h1[2], d0[2], d1[2];   // d = 2*c; tanh(c) = 2*sigma(d) - 1

    // ---- t = 0 (h = c = 0): f-gate unused ----
#pragma unroll
    for (int e = 0; e < 2; ++e) {
        const float yi0 = fmaf(ws[0], xs[e][0], bb[0]);
        const float yi1 = fmaf(ws[1], xs[e][0], bb[1]);
        const float yg0 = fmaf(ws[4], xs[e][0], bb[4]);
        const float yg1 = fmaf(ws[5], xs[e][0], bb[5]);
        const float yo0 = fmaf(ws[6], xs[e][0], bb[6]);
        const float yo1 = fmaf(ws[7], xs[e][0], bb[7]);
        const float si0 = tab[(unsigned)yi0];
        const float si1 = tab[(unsigned)yi1];
        const float sg0 = tab[(unsigned)gclamp(yg0)];
        const float sg1 = tab[(unsigned)gclamp(yg1)];
        const float so0 = tab[(unsigned)yo0];
        const float so1 = tab[(unsigned)yo1];
        d0[e] = si0 * fmaf(4.0f, sg0, -2.0f);      // i * 2*tanh(g)
        d1[e] = si1 * fmaf(4.0f, sg1, -2.0f);
        const float sd0 = tab[(unsigned)fmaf(d0[e], 256.0f, 2048.5f)];
        const float sd1 = tab[(unsigned)fmaf(d1[e], 256.0f, 2048.5f)];
        h0[e] = fmaf(2.0f, so0 * sd0, -so0);       // o * (2*sigma(d) - 1)
        h1[e] = fmaf(2.0f, so1 * sd1, -so1);
    }

    // ---- t = 1..3 ----
#pragma unroll
    for (int t = 1; t < 4; ++t) {
#pragma unroll
        for (int e = 0; e < 2; ++e) {
            float y[8];
#pragma unroll
            for (int g = 0; g < 8; ++g)
                y[g] = fmaf(ws[g], xs[e][t],
                       fmaf(w0[g], h0[e],
                       fmaf(w1[g], h1[e], bb[g])));
            const float si0 = tab[(unsigned)y[0]];
            const float si1 = tab[(unsigned)y[1]];
            const float sf0 = tab[(unsigned)y[2]];
            const float sf1 = tab[(unsigned)y[3]];
            const float sg0 = tab[(unsigned)gclamp(y[4])];
            const float sg1 = tab[(unsigned)gclamp(y[5])];
            const float so0 = tab[(unsigned)y[6]];
            const float so1 = tab[(unsigned)y[7]];
            d0[e] = fmaf(sf0, d0[e], si0 * fmaf(4.0f, sg0, -2.0f));
            d1[e] = fmaf(sf1, d1[e], si1 * fmaf(4.0f, sg1, -2.0f));
            const float sd0 = tab[(unsigned)fmaf(d0[e], 256.0f, 2048.5f)];
            const float sd1 = tab[(unsigned)fmaf(d1[e], 256.0f, 2048.5f)];
            h0[e] = fmaf(2.0f, so0 * sd0, -so0);
            h1[e] = fmaf(2.0f, so1 * sd1, -so1);
        }
    }

    out[tid]        = fmaf(wfc0, h0[0], fmaf(wfc1, h1[0], bfc));
    out[tid + half] = fmaf(wfc0, h0[1], fmaf(wfc1, h1[1], bfc));
}

extern "C" void kernel_launch(void* const* d_in, const int* in_sizes, int n_in,
                              void* d_out, int out_size, void* d_ws, size_t ws_size,
                              hipStream_t stream) {
    const float4* x4   = (const float4*)d_in[0];
    const float*  W_ih = (const float*)d_in[1];
    const float*  W_hh = (const float*)d_in[2];
    const float*  b_ih = (const float*)d_in[3];
    const float*  b_hh = (const float*)d_in[4];
    const float*  W_fc = (const float*)d_in[5];
    const float*  b_fc = (const float*)d_in[6];
    float* out = (float*)d_out;

    const int B = out_size;                  // 2,097,152
    const int half = B >> 1;
    const int block = 256;
    const int grid = (half + block - 1) / block;   // 4096 blocks, 2 elems/thread
    lstm_fc_nn<<<grid, block, 0, stream>>>(x4, W_ih, W_hh, b_ih, b_hh,
                                           W_fc, b_fc, out, B);
}

// Round 4
// 24.626 us; speedup vs baseline: 1.0153x; 1.0153x over previous
//
#include <hip/hip_runtime.h>
#include <hip/hip_bf16.h>

// Conflict-free replicated sigmoid lerp table.
//   256 cells over [-8, 8], step 1/16. Entry = float2{ value, slope }.
//   16 copies, interleaved: entry i of copy c lives at tab2[i*16 + c]
//   -> dword addr 32*i + 2*c -> banks {2c, 2c+1} for ALL i.
//   Lane l uses copy (l & 15): each bank serves exactly 4 lanes x 1 dword
//   per wave64 ds_read_b64 = the hardware minimum. Zero bank conflicts
//   regardless of the (data-dependent) index distribution.
// Index space folded into weights: y = 16*x + 128 (32*x for g-gates,
// tanh(g) = 2*sigma(2g) - 1).

__device__ __forceinline__ float lutl(const float2* __restrict__ tab2,
                                      unsigned copy, float y) {
    const unsigned iy = (unsigned)y;
    const float    fy = y - (float)iy;
    const float2   vs = tab2[iy * 16u + copy];
    return fmaf(vs.y, fy, vs.x);
}

__device__ __forceinline__ float gclamp(float y) {
    return __builtin_amdgcn_fmed3f(y, 0.0f, 255.999f);
}

__global__ __launch_bounds__(256) void lstm_fc_cfree(
    const float4* __restrict__ x4,     // [B] float4 (SEQ=4, INPUT=1)
    const float*  __restrict__ W_ih,   // [8]
    const float*  __restrict__ W_hh,   // [8,2]
    const float*  __restrict__ b_ih,   // [8]
    const float*  __restrict__ b_hh,   // [8]
    const float*  __restrict__ W_fc,   // [1,2]
    const float*  __restrict__ b_fc,   // [1]
    float* __restrict__ out,           // [B]
    int B)
{
    __shared__ float2 tab2[256 * 16];  // 32 KB
    __shared__ float  vtmp[257];

    {   // build: 2 trans ops per thread, then replicate 16x (rotated -> no
        // write conflicts: for fixed j, lanes t,t+16,t+32,t+48 share a bank
        // pair with distinct rows = 4 dwords/bank = b64 minimum).
        const int t = threadIdx.x;     // exactly 256 threads
        const float xv = fmaf((float)t, 0.0625f, -8.0f);
        vtmp[t] = __fdividef(1.0f, 1.0f + __expf(-xv));
        if (t == 0) vtmp[256] = __fdividef(1.0f, 1.0f + __expf(-8.0f));
        __syncthreads();
        const float val = vtmp[t];
        const float slp = vtmp[t + 1] - val;
#pragma unroll
        for (int j = 0; j < 16; ++j) {
            const int c = (t + j) & 15;
            tab2[t * 16 + c] = make_float2(val, slp);
        }
        __syncthreads();
    }

    // Gate order [i,f,g,o] x H=2: 0,1=i  2,3=f  4,5=g  6,7=o.
    float ws[8], w0[8], w1[8], bb[8];
#pragma unroll
    for (int g = 0; g < 8; ++g) {
        const float s = (g == 4 || g == 5) ? 32.0f : 16.0f;
        ws[g] = s * W_ih[g];
        w0[g] = s * W_hh[2 * g];
        w1[g] = s * W_hh[2 * g + 1];
        bb[g] = fmaf(s, b_ih[g] + b_hh[g], 128.0f);
    }
    const float wfc0 = W_fc[0], wfc1 = W_fc[1], bfc = b_fc[0];

    const unsigned copy = threadIdx.x & 15u;
    const int half = B >> 1;
    const int tid = blockIdx.x * blockDim.x + threadIdx.x;
    if (tid >= half) return;

    // Two independent elements per thread for ILP on the serial chain.
    const float4 xa = x4[tid];
    const float4 xb = x4[tid + half];
    const float xs[2][4] = {{xa.x, xa.y, xa.z, xa.w}, {xb.x, xb.y, xb.z, xb.w}};

    float h0[2], h1[2], d0[2], d1[2];   // d = 2*c; tanh(c) = 2*sigma(d) - 1

    // ---- t = 0 (h = c = 0): f-gate unused ----
#pragma unroll
    for (int e = 0; e < 2; ++e) {
        const float yi0 = fmaf(ws[0], xs[e][0], bb[0]);
        const float yi1 = fmaf(ws[1], xs[e][0], bb[1]);
        const float yg0 = gclamp(fmaf(ws[4], xs[e][0], bb[4]));
        const float yg1 = gclamp(fmaf(ws[5], xs[e][0], bb[5]));
        const float yo0 = fmaf(ws[6], xs[e][0], bb[6]);
        const float yo1 = fmaf(ws[7], xs[e][0], bb[7]);
        const float si0 = lutl(tab2, copy, yi0);
        const float si1 = lutl(tab2, copy, yi1);
        const float sg0 = lutl(tab2, copy, yg0);
        const float sg1 = lutl(tab2, copy, yg1);
        const float so0 = lutl(tab2, copy, yo0);
        const float so1 = lutl(tab2, copy, yo1);
        d0[e] = si0 * fmaf(4.0f, sg0, -2.0f);      // i * 2*tanh(g)
        d1[e] = si1 * fmaf(4.0f, sg1, -2.0f);
        const float sd0 = lutl(tab2, copy, fmaf(d0[e], 16.0f, 128.0f));
        const float sd1 = lutl(tab2, copy, fmaf(d1[e], 16.0f, 128.0f));
        h0[e] = fmaf(2.0f, so0 * sd0, -so0);       // o * (2*sigma(d) - 1)
        h1[e] = fmaf(2.0f, so1 * sd1, -so1);
    }

    // ---- t = 1..3 ----
#pragma unroll
    for (int t = 1; t < 4; ++t) {
#pragma unroll
        for (int e = 0; e < 2; ++e) {
            float y[8];
#pragma unroll
            for (int g = 0; g < 8; ++g)
                y[g] = fmaf(ws[g], xs[e][t],
                       fmaf(w0[g], h0[e],
                       fmaf(w1[g], h1[e], bb[g])));
            const float si0 = lutl(tab2, copy, y[0]);
            const float si1 = lutl(tab2, copy, y[1]);
            const float sf0 = lutl(tab2, copy, y[2]);
            const float sf1 = lutl(tab2, copy, y[3]);
            const float sg0 = lutl(tab2, copy, gclamp(y[4]));
            const float sg1 = lutl(tab2, copy, gclamp(y[5]));
            const float so0 = lutl(tab2, copy, y[6]);
            const float so1 = lutl(tab2, copy, y[7]);
            d0[e] = fmaf(sf0, d0[e], si0 * fmaf(4.0f, sg0, -2.0f));
            d1[e] = fmaf(sf1, d1[e], si1 * fmaf(4.0f, sg1, -2.0f));
            const float sd0 = lutl(tab2, copy, fmaf(d0[e], 16.0f, 128.0f));
            const float sd1 = lutl(tab2, copy, fmaf(d1[e], 16.0f, 128.0f));
            h0[e] = fmaf(2.0f, so0 * sd0, -so0);
            h1[e] = fmaf(2.0f, so1 * sd1, -so1);
        }
    }

    out[tid]        = fmaf(wfc0, h0[0], fmaf(wfc1, h1[0], bfc));
    out[tid + half] = fmaf(wfc0, h0[1], fmaf(wfc1, h1[1], bfc));
}

extern "C" void kernel_launch(void* const* d_in, const int* in_sizes, int n_in,
                              void* d_out, int out_size, void* d_ws, size_t ws_size,
                              hipStream_t stream) {
    const float4* x4   = (const float4*)d_in[0];
    const float*  W_ih = (const float*)d_in[1];
    const float*  W_hh = (const float*)d_in[2];
    const float*  b_ih = (const float*)d_in[3];
    const float*  b_hh = (const float*)d_in[4];
    const float*  W_fc = (const float*)d_in[5];
    const float*  b_fc = (const float*)d_in[6];
    float* out = (float*)d_out;

    const int B = out_size;                  // 2,097,152
    const int half = B >> 1;
    const int block = 256;
    const int grid = (half + block - 1) / block;   // 4096 blocks, 2 elems/thread
    lstm_fc_cfree<<<grid, block, 0, stream>>>(x4, W_ih, W_hh, b_ih, b_hh,
                                              W_fc, b_fc, out, B);
}